// Round 4
// baseline (312.109 us; speedup 1.0000x reference)
//
#include <hip/hip_runtime.h>
#include <math.h>

#define TW 16                // tile width (output cols)
#define THT 32               // tile height: 42-row halo -> 20528 B LDS -> 7 blocks/CU
#define HRT 42               // THT + 10
#define SS 58                // sb row stride: 28 px * 2 (u,v interleaved) + 2 pad.
                             // 29r+x mod 16 (29 odd) -> phase-2 b64 taps uniform
                             // 4 lanes/bank (HW minimum, verified r1/r3).
#define HS 64                // hb row stride: 16 cols * 4 packed (mu,mv,qu,qv).
                             // Column-quad XOR by row parity: b128 read/write uniform-8.
#define SC1 0.0001f
#define SC2 0.0009f
#define PLANES 48
#define NSLOT 64

// u/v transform staged at load: u=a+b, v=a-b, INTERLEAVED in one buffer.
// 4 windowed quantities (mu,mv,qu,qv) packed per column in hb.
// Epilogue recovery identical to r8/r9-verified algebra.
// r3 result: conflicts -81% but VALUBusy stuck at 49%, occupancy 39% (4 blk/CU,
// LDS-capped) -> latency-bound. This round: THt 64->32 for 7 blk/CU (28 waves).
struct alignas(16) Smem {
    float sb[HRT * SS];      // (u,v) interleaved: pixel x at [SS*r + 2x]
    float hb[HRT * HS];      // float4 (mu,mv,qu,qv) at [HS*r + (4c ^ ((r&1)<<2))]
    float rbuf[8];
};
// (42*58 + 42*64 + 8)*4 = 20528 B -> 7 blocks/CU (163840/20528 = 7.98).

__device__ __forceinline__ void ssim_tile(
        Smem* sm,
        const float* __restrict__ p1, const float* __restrict__ p2,
        int H, int W, int tx, int ty, int level,
        const float* __restrict__ window,
        float* __restrict__ accum,
        float* __restrict__ l1a, float* __restrict__ l1b,   // plane-offset outs (or null)
        float* __restrict__ l2a, float* __restrict__ l2b,
        float* __restrict__ l3a, float* __restrict__ l3b,
        float* __restrict__ l4a, float* __restrict__ l4b)
{
    const int tid = threadIdx.x;
    float* sb = sm->sb;
    float* hb = sm->hb;

    // 1D gaussian from 2D window: g[k] = w2[5][k]/sqrt(w2[5][5])
    float g[11];
    {
        float invg5 = 1.0f / sqrtf(window[60]);
        #pragma unroll
        for (int k = 0; k < 11; ++k) g[k] = window[55 + k] * invg5;
    }

    // ---- Phase 1: stage halo tile (HRT x 28 px) as interleaved (u,v) ----
    const bool interior = (ty >= 5) && (ty + HRT - 6 < H) &&
                          (tx >= 6) && (tx + 22 <= W);
    if (interior) {
        for (int s = tid; s < HRT * 14; s += 256) {
            int r = s / 14, j = s - r * 14;
            size_t o = (size_t)(ty + r - 5) * W + (tx - 6 + 2 * j);
            float2 v1 = *(const float2*)(p1 + o);
            float2 v2 = *(const float2*)(p2 + o);
            float* d = &sb[SS * r + 4 * j];
            *(float2*)(d)     = make_float2(v1.x + v2.x, v1.x - v2.x);
            *(float2*)(d + 2) = make_float2(v1.y + v2.y, v1.y - v2.y);
        }
    } else {
        for (int s = tid; s < HRT * 14; s += 256) {
            int r = s / 14, j = s - r * 14;
            int gy = ty + r - 5;
            int gx = tx - 6 + 2 * j;
            float2 v1 = make_float2(0.f, 0.f), v2 = make_float2(0.f, 0.f);
            if ((unsigned)gy < (unsigned)H && (unsigned)gx < (unsigned)W) {
                size_t o = (size_t)gy * W + gx;
                v1 = *(const float2*)(p1 + o);
                v2 = *(const float2*)(p2 + o);
            }
            float* d = &sb[SS * r + 4 * j];
            *(float2*)(d)     = make_float2(v1.x + v2.x, v1.x - v2.x);
            *(float2*)(d + 2) = make_float2(v1.y + v2.y, v1.y - v2.y);
        }
    }
    __syncthreads();

    // ---- Fused 2x2 avg-pool -> l1 (128 threads; a=(u+v)/2) ----
    if (l1a && tid < 4 * THT) {
        int pc = tid & 7;          // pooled col 0..7
        int pr = tid >> 3;         // pooled row 0..THT/2-1
        int r  = 2 * pr + 5;
        int x0 = 2 * (2 * pc + 6); // float offset of pixel within row
        const float* a0 = &sb[SS * r + x0];
        float2 p00 = *(const float2*)(a0);
        float2 p01 = *(const float2*)(a0 + 2);
        float2 p10 = *(const float2*)(a0 + SS);
        float2 p11 = *(const float2*)(a0 + SS + 2);
        float su = p00.x + p01.x + p10.x + p11.x;
        float sv = p00.y + p01.y + p10.y + p11.y;
        int W2 = W >> 1;
        size_t o = (size_t)((ty >> 1) + pr) * W2 + (tx >> 1) + pc;
        l1a[o] = 0.125f * (su + sv);
        l1b[o] = 0.125f * (su - sv);
    }

    // ---- Pyramid l2/l3/l4 on wave 3 (THT=32: 32 l2 px, lanes 0..31) ----
    if (l1a && tid >= 192 && tid < 192 + THT) {
        const int lane = tid - 192;
        int qr = lane >> 2, qc = lane & 3;      // l2 px = 4x4 mean of originals
        int rb = 4 * qr + 5, cb = 4 * qc + 6;   // qr 0..7, qc 0..3
        float su = 0.f, sv = 0.f;
        #pragma unroll
        for (int i = 0; i < 4; ++i) {
            int ii = (i + qc) & 3;              // sum-invariant rotations:
            #pragma unroll
            for (int j = 0; j < 4; ++j) {
                int jr = (j + qr) & 3;          // spread banks across lanes
                float2 p = *(const float2*)&sb[SS * (rb + ii) + 2 * (cb + jr)];
                su += p.x; sv += p.y;
            }
        }
        float v2a = 0.03125f * (su + sv), v2b = 0.03125f * (su - sv);
        {
            int W4 = W >> 2;
            size_t o = (size_t)((ty >> 2) + qr) * W4 + (tx >> 2) + qc;
            l2a[o] = v2a;
            l2b[o] = v2b;
        }
        float v3a, v3b;
        {
            int tr = (lane >> 1) & 3, tc = lane & 1;    // l3: 4 rows x 2 cols
            int l00 = 8 * tr + 2 * tc;
            v3a = 0.25f * (__shfl(v2a, l00) + __shfl(v2a, l00 + 1) +
                           __shfl(v2a, l00 + 4) + __shfl(v2a, l00 + 5));
            v3b = 0.25f * (__shfl(v2b, l00) + __shfl(v2b, l00 + 1) +
                           __shfl(v2b, l00 + 4) + __shfl(v2b, l00 + 5));
            if (lane < 8) {
                int W8 = W >> 3;
                size_t o = (size_t)((ty >> 3) + tr) * W8 + (tx >> 3) + tc;
                l3a[o] = v3a;
                l3b[o] = v3b;
            }
        }
        {
            int ur = lane & 1;                          // l4: 2 rows x 1 col
            float v4a = 0.25f * (__shfl(v3a, 4 * ur) + __shfl(v3a, 4 * ur + 1) +
                                 __shfl(v3a, 4 * ur + 2) + __shfl(v3a, 4 * ur + 3));
            float v4b = 0.25f * (__shfl(v3b, 4 * ur) + __shfl(v3b, 4 * ur + 1) +
                                 __shfl(v3b, 4 * ur + 2) + __shfl(v3b, 4 * ur + 3));
            if (lane < 2) {
                int W16 = W >> 4;
                size_t o = (size_t)((ty >> 4) + ur) * W16 + (tx >> 4);
                l4a[o] = v4a;
                l4b[o] = v4b;
            }
        }
    }

    // ---- Phase 2: horizontal 11-tap, 336 items over 256 threads ----
    // 12 aligned b64 tap reads (conflict-free), 2 b128 swizzled writes (uniform-8).
    for (int gi = tid; gi < HRT * 8; gi += 256) {
        int r  = gi >> 3;
        int c0 = (gi & 7) << 1;
        const float* src = &sb[SS * r + 2 * (c0 + 1)];
        float mua = 0, mva = 0, qua = 0, qva = 0;
        float mub = 0, mvb = 0, qub = 0, qvb = 0;
        #pragma unroll
        for (int k = 0; k < 12; ++k) {              // taps x = c0+1 .. c0+12
            float2 uv = *(const float2*)(src + 2 * k);
            float u = uv.x, v = uv.y;
            float u2 = u * u, v2 = v * v;
            if (k < 11) {
                float gk = g[k];
                mua = fmaf(gk, u,  mua);
                mva = fmaf(gk, v,  mva);
                qua = fmaf(gk, u2, qua);
                qva = fmaf(gk, v2, qva);
            }
            if (k >= 1) {
                float gk = g[k - 1];
                mub = fmaf(gk, u,  mub);
                mvb = fmaf(gk, v,  mvb);
                qub = fmaf(gk, u2, qub);
                qvb = fmaf(gk, v2, qvb);
            }
        }
        int rx = (r & 1) << 2;
        *(float4*)&hb[HS * r + ((4 * c0)     ^ rx)] = make_float4(mua, mva, qua, qva);
        *(float4*)&hb[HS * r + ((4 * c0 + 4) ^ rx)] = make_float4(mub, mvb, qub, qvb);
    }
    __syncthreads();

    // ---- Phase 3: vertical 11-tap, 256 threads x 2 stacked rows ----
    // 12 b128 reads/thread; one read yields all 4 quantities.
    // All tile heights divide H exactly (32 | {512,256,128,64,32}) -> no row guard.
    float ssum = 0.f, csum = 0.f;
    {
        int c  = tid & 15;              // output col 0..15
        int r0 = (tid >> 4) << 1;       // output rows r0, r0+1 (0..30)
        float MU[2] = {0, 0}, MV[2] = {0, 0};
        float QU[2] = {0, 0}, QV[2] = {0, 0};
        #pragma unroll
        for (int k = 0; k < 12; ++k) {
            int R = r0 + k;
            float4 h = *(const float4*)&hb[HS * R + ((4 * c) ^ ((R & 1) << 2))];
            #pragma unroll
            for (int j = 0; j < 2; ++j) {
                int t = k - j;
                if (t >= 0 && t < 11) {
                    float gk = g[t];
                    MU[j] = fmaf(gk, h.x, MU[j]);
                    MV[j] = fmaf(gk, h.y, MV[j]);
                    QU[j] = fmaf(gk, h.z, QU[j]);
                    QV[j] = fmaf(gk, h.w, QV[j]);
                }
            }
        }
        #pragma unroll
        for (int j = 0; j < 2; ++j) {
            float P = MU[j] * MU[j], Qm = MV[j] * MV[j];
            float A = 0.5f * (P - Qm);            // 2*mu1*mu2
            float B = 0.5f * (P + Qm);            // mu1^2 + mu2^2
            float su = 0.5f * (QU[j] + QV[j]);    // E[x^2] + E[y^2]
            float sd = 0.5f * (QU[j] - QV[j]);    // 2*E[xy]
            float n1 = A + SC1;
            float d1 = B + SC1;
            float n2 = sd - A + SC2;              // 2*sigma12 + C2
            float d2 = su - B + SC2;              // sigma1^2+sigma2^2 + C2
            float inv = 1.f / (d1 * d2);
            csum += n2 * d1 * inv;
            ssum += n1 * n2 * inv;
        }
    }

    // ---- Block reduction -> one atomic pair per block ----
    #pragma unroll
    for (int off = 32; off; off >>= 1) {
        ssum += __shfl_down(ssum, off);
        csum += __shfl_down(csum, off);
    }
    const int wid = tid >> 6, lane = tid & 63;
    if (lane == 0) { sm->rbuf[wid * 2] = ssum; sm->rbuf[wid * 2 + 1] = csum; }
    __syncthreads();
    if (tid == 0) {
        float S = sm->rbuf[0] + sm->rbuf[2] + sm->rbuf[4] + sm->rbuf[6];
        float C = sm->rbuf[1] + sm->rbuf[3] + sm->rbuf[5] + sm->rbuf[7];
        int slot = (blockIdx.x + blockIdx.y * 7 + blockIdx.z * 13) & (NSLOT - 1);
        atomicAdd(&accum[(2 * level) * NSLOT + slot], S);
        atomicAdd(&accum[(2 * level + 1) * NSLOT + slot], C);
    }
}

// ---------------- level 0: 16x32 tiles, SSIM + full pyramid ---------------
__global__ __launch_bounds__(256, 7) void ssim_l0(
        const float* __restrict__ img1, const float* __restrict__ img2,
        const float* __restrict__ window, float* __restrict__ accum,
        float* __restrict__ l1a, float* __restrict__ l1b,
        float* __restrict__ l2a, float* __restrict__ l2b,
        float* __restrict__ l3a, float* __restrict__ l3b,
        float* __restrict__ l4a, float* __restrict__ l4b)
{
    __shared__ Smem sm;
    const int plane = blockIdx.z;
    ssim_tile(&sm,
              img1 + (size_t)plane * 512 * 512,
              img2 + (size_t)plane * 512 * 512,
              512, 512, blockIdx.x * TW, blockIdx.y * THT, 0,
              window, accum,
              l1a + (size_t)plane * 256 * 256, l1b + (size_t)plane * 256 * 256,
              l2a + (size_t)plane * 128 * 128, l2b + (size_t)plane * 128 * 128,
              l3a + (size_t)plane * 64 * 64,   l3b + (size_t)plane * 64 * 64,
              l4a + (size_t)plane * 32 * 32,   l4b + (size_t)plane * 32 * 32);
}

// ---------------- combined levels 1-4: 16x32 tiles ------------------------
// l1: 16x8=128 tiles, l2: 8x4=32, l3: 4x2=8, l4: 2x1=2 -> 170 blocks/plane.
__global__ __launch_bounds__(256, 7) void ssim_rest(
        const float* __restrict__ l1a, const float* __restrict__ l1b,
        const float* __restrict__ l2a, const float* __restrict__ l2b,
        const float* __restrict__ l3a, const float* __restrict__ l3b,
        const float* __restrict__ l4a, const float* __restrict__ l4b,
        const float* __restrict__ window, float* __restrict__ accum)
{
    __shared__ Smem sm;
    const int x = blockIdx.x;        // 0..169 tile id within plane
    const int plane = blockIdx.z;
    int level, H, tix, tiy;
    const float *b1, *b2;
    if (x < 128)      { level = 1; H = 256; tix = x & 15;            tiy = x >> 4;        b1 = l1a; b2 = l1b; }
    else if (x < 160) { level = 2; H = 128; int i = x - 128; tix = i & 7; tiy = i >> 3;   b1 = l2a; b2 = l2b; }
    else if (x < 168) { level = 3; H = 64;  int i = x - 160; tix = i & 3; tiy = i >> 2;   b1 = l3a; b2 = l3b; }
    else              { level = 4; H = 32;  int i = x - 168; tix = i;     tiy = 0;        b1 = l4a; b2 = l4b; }
    const float* p1 = b1 + (size_t)plane * H * H;
    const float* p2 = b2 + (size_t)plane * H * H;
    ssim_tile(&sm, p1, p2, H, H, tix * TW, tiy * THT, level,
              window, accum,
              nullptr, nullptr, nullptr, nullptr,
              nullptr, nullptr, nullptr, nullptr);
}

// ---------------- final weighted product ----------------------------------
__global__ void finalize_kernel(const float* __restrict__ accum, float* __restrict__ out) {
    int t = threadIdx.x;   // 64 threads
    float sums[10];
    #pragma unroll
    for (int i = 0; i < 10; ++i) {
        float v = accum[i * NSLOT + t];
        #pragma unroll
        for (int off = 32; off; off >>= 1) v += __shfl_down(v, off);
        sums[i] = v;
    }
    if (t == 0) {
        const float w[5] = {0.0448f, 0.2856f, 0.3001f, 0.2363f, 0.1333f};
        float res = 1.f;
        #pragma unroll
        for (int L = 0; L < 4; ++L) {
            float dim = (float)(512 >> L);
            float cnt = (float)PLANES * dim * dim;
            res *= powf(sums[2 * L + 1] / cnt, w[L]);   // cs mean, levels 0..3
        }
        float cnt4 = (float)PLANES * 32.f * 32.f;
        res *= powf(sums[8] / cnt4, w[4]);              // ssim mean, level 4
        out[0] = res;
    }
}

// ---------------- launch ---------------------------------------------------
extern "C" void kernel_launch(void* const* d_in, const int* in_sizes, int n_in,
                              void* d_out, int out_size, void* d_ws, size_t ws_size,
                              hipStream_t stream) {
    const float* img1   = (const float*)d_in[0];
    const float* img2   = (const float*)d_in[1];
    const float* window = (const float*)d_in[2];
    float* out = (float*)d_out;
    float* ws  = (float*)d_ws;

    float* accum = ws;   // 640 floats
    const size_t S1 = (size_t)PLANES * 256 * 256;
    const size_t S2 = (size_t)PLANES * 128 * 128;
    const size_t S3 = (size_t)PLANES * 64 * 64;
    const size_t S4 = (size_t)PLANES * 32 * 32;
    float* l1a = ws + 1024;    float* l1b = l1a + S1;
    float* l2a = l1b + S1;     float* l2b = l2a + S2;
    float* l3a = l2b + S2;     float* l3b = l3a + S3;
    float* l4a = l3b + S3;     float* l4b = l4a + S4;

    hipMemsetAsync(accum, 0, 10 * NSLOT * sizeof(float), stream);

    ssim_l0<<<dim3(512 / TW, 512 / THT, PLANES), 256, 0, stream>>>(
        img1, img2, window, accum,
        l1a, l1b, l2a, l2b, l3a, l3b, l4a, l4b);

    ssim_rest<<<dim3(170, 1, PLANES), 256, 0, stream>>>(
        l1a, l1b, l2a, l2b, l3a, l3b, l4a, l4b, window, accum);

    finalize_kernel<<<1, 64, 0, stream>>>(accum, out);
}

// Round 5
// 222.521 us; speedup vs baseline: 1.4026x; 1.4026x over previous
//
#include <hip/hip_runtime.h>
#include <math.h>

#define TW 16                // tile width (output cols)
#define THT 64               // tile height (r4 post-mortem: THT=32 regressed 37%)
#define HRT 74               // THT + 10
#define SS 66                // sb row stride: 32 px * 2 (u,v interleaved) + 2 pad.
                             // b64 slot stride 33 == 1 mod 16 -> phase-2 taps
                             // uniform 4 lanes/bank (hand-verified r5).
#define HS 64                // hb row stride: 16 cols * 4 packed (mu,mv,qu,qv).
                             // Column-quad XOR by row parity: b128 read/write uniform-8.
#define SC1 0.0001f
#define SC2 0.0009f
#define PLANES 48
#define NSLOT 64

// u/v transform staged at load: u=a+b, v=a-b, INTERLEAVED in one buffer.
// Staged window = cols tx-8 .. tx+23 (32 px): 16B-aligned -> float4 global loads.
// Output col c uses staged cols c+3 .. c+13.
// 4 windowed quantities (mu,mv,qu,qv) packed per column in hb (r3-verified).
struct alignas(16) Smem {
    float sb[HRT * SS];      // (u,v) interleaved: staged px j at [SS*r + 2j]
    float hb[HRT * HS];      // float4 (mu,mv,qu,qv) at [HS*r + (4c ^ ((r&1)<<2))]
    float rbuf[8];
};
// (74*66 + 74*64 + 8)*4 = 38512 B -> 4 blocks/CU.

__device__ __forceinline__ void ssim_tile(
        Smem* sm,
        const float* __restrict__ p1, const float* __restrict__ p2,
        int H, int W, int tx, int ty, int level,
        const float* __restrict__ window,
        float* __restrict__ accum,
        float* __restrict__ l1a, float* __restrict__ l1b,   // plane-offset outs (or null)
        float* __restrict__ l2a, float* __restrict__ l2b,
        float* __restrict__ l3a, float* __restrict__ l3b,
        float* __restrict__ l4a, float* __restrict__ l4b)
{
    const int tid = threadIdx.x;
    float* sb = sm->sb;
    float* hb = sm->hb;

    // 1D gaussian from 2D window: g[k] = w2[5][k]/sqrt(w2[5][5])
    float g[11];
    {
        float invg5 = 1.0f / sqrtf(window[60]);
        #pragma unroll
        for (int k = 0; k < 11; ++k) g[k] = window[55 + k] * invg5;
    }

    // ---- Phase 1: stage halo tile (HRT x 32 px) as interleaved (u,v) ----
    const bool interior = (ty >= 5) && (ty + HRT - 6 < H) &&
                          (tx >= 8) && (tx + 24 <= W);
    if (interior) {
        // 592 items, float4 loads (16B-aligned: tx-8+4j == 0 mod 4)
        for (int s = tid; s < HRT * 8; s += 256) {
            int r = s >> 3, j = s & 7;
            size_t o = (size_t)(ty + r - 5) * W + (tx - 8 + 4 * j);
            float4 a = *(const float4*)(p1 + o);
            float4 b = *(const float4*)(p2 + o);
            float* d = &sb[SS * r + 8 * j];
            *(float2*)(d)     = make_float2(a.x + b.x, a.x - b.x);
            *(float2*)(d + 2) = make_float2(a.y + b.y, a.y - b.y);
            *(float2*)(d + 4) = make_float2(a.z + b.z, a.z - b.z);
            *(float2*)(d + 6) = make_float2(a.w + b.w, a.w - b.w);
        }
    } else {
        // boundary: float2 slots with whole-slot guard (gx even, W even)
        for (int s = tid; s < HRT * 16; s += 256) {
            int r = s >> 4, j = s & 15;
            int gy = ty + r - 5;
            int gx = tx - 8 + 2 * j;
            float2 v1 = make_float2(0.f, 0.f), v2 = make_float2(0.f, 0.f);
            if ((unsigned)gy < (unsigned)H && (unsigned)gx < (unsigned)W) {
                size_t o = (size_t)gy * W + gx;
                v1 = *(const float2*)(p1 + o);
                v2 = *(const float2*)(p2 + o);
            }
            float* d = &sb[SS * r + 4 * j];
            *(float2*)(d)     = make_float2(v1.x + v2.x, v1.x - v2.x);
            *(float2*)(d + 2) = make_float2(v1.y + v2.y, v1.y - v2.y);
        }
    }
    __syncthreads();

    // ---- Fused 2x2 avg-pool -> l1 (all 256 threads; a=(u+v)/2) ----
    if (l1a) {
        int pc = tid & 7;          // pooled col 0..7
        int pr = tid >> 3;         // pooled row 0..31
        int r  = 2 * pr + 5;
        int x0 = 2 * (2 * pc + 8); // staged col of original px 2pc
        const float* a0 = &sb[SS * r + x0];
        float2 p00 = *(const float2*)(a0);
        float2 p01 = *(const float2*)(a0 + 2);
        float2 p10 = *(const float2*)(a0 + SS);
        float2 p11 = *(const float2*)(a0 + SS + 2);
        float su = p00.x + p01.x + p10.x + p11.x;
        float sv = p00.y + p01.y + p10.y + p11.y;
        int W2 = W >> 1;
        size_t o = (size_t)((ty >> 1) + pr) * W2 + (tx >> 1) + pc;
        l1a[o] = 0.125f * (su + sv);
        l1b[o] = 0.125f * (su - sv);
    }

    // ---- Pyramid l2/l3/l4 on wave 3 (64 l2 px = full wave) ----
    if (l1a && tid >= 192) {
        const int lane = tid - 192;
        int qr = lane >> 2, qc = lane & 3;      // l2 px = 4x4 mean of originals
        int rb = 4 * qr + 5, cb = 4 * qc + 8;   // cb in staged-col space
        float su = 0.f, sv = 0.f;
        #pragma unroll
        for (int i = 0; i < 4; ++i) {
            int ii = (i + qc) & 3;              // sum-invariant rotations:
            #pragma unroll
            for (int j = 0; j < 4; ++j) {
                int jr = (j + qr) & 3;          // spread banks across lanes
                float2 p = *(const float2*)&sb[SS * (rb + ii) + 2 * (cb + jr)];
                su += p.x; sv += p.y;
            }
        }
        float v2a = 0.03125f * (su + sv), v2b = 0.03125f * (su - sv);
        {
            int W4 = W >> 2;
            size_t o = (size_t)((ty >> 2) + qr) * W4 + (tx >> 2) + qc;
            l2a[o] = v2a;
            l2b[o] = v2b;
        }
        float v3a, v3b;
        {
            int tr = (lane >> 1) & 7, tc = lane & 1;
            int l00 = 8 * tr + 2 * tc;
            v3a = 0.25f * (__shfl(v2a, l00) + __shfl(v2a, l00 + 1) +
                           __shfl(v2a, l00 + 4) + __shfl(v2a, l00 + 5));
            v3b = 0.25f * (__shfl(v2b, l00) + __shfl(v2b, l00 + 1) +
                           __shfl(v2b, l00 + 4) + __shfl(v2b, l00 + 5));
            if (lane < 16) {
                int W8 = W >> 3;
                size_t o = (size_t)((ty >> 3) + tr) * W8 + (tx >> 3) + tc;
                l3a[o] = v3a;
                l3b[o] = v3b;
            }
        }
        {
            int ur = lane & 3;
            float v4a = 0.25f * (__shfl(v3a, 4 * ur) + __shfl(v3a, 4 * ur + 1) +
                                 __shfl(v3a, 4 * ur + 2) + __shfl(v3a, 4 * ur + 3));
            float v4b = 0.25f * (__shfl(v3b, 4 * ur) + __shfl(v3b, 4 * ur + 1) +
                                 __shfl(v3b, 4 * ur + 2) + __shfl(v3b, 4 * ur + 3));
            if (lane < 4) {
                int W16 = W >> 4;
                size_t o = (size_t)((ty >> 4) + ur) * W16 + (tx >> 4);
                l4a[o] = v4a;
                l4b[o] = v4b;
            }
        }
    }

    // ---- Phase 2: horizontal 11-tap, 592 items over 256 threads ----
    // Output col c taps staged cols c+3..c+13; item covers c0, c0+1.
    for (int gi = tid; gi < HRT * 8; gi += 256) {
        int r  = gi >> 3;
        int c0 = (gi & 7) << 1;
        const float* src = &sb[SS * r + 2 * (c0 + 3)];
        float mua = 0, mva = 0, qua = 0, qva = 0;
        float mub = 0, mvb = 0, qub = 0, qvb = 0;
        #pragma unroll
        for (int k = 0; k < 12; ++k) {              // staged cols c0+3 .. c0+14
            float2 uv = *(const float2*)(src + 2 * k);
            float u = uv.x, v = uv.y;
            float u2 = u * u, v2 = v * v;
            if (k < 11) {
                float gk = g[k];
                mua = fmaf(gk, u,  mua);
                mva = fmaf(gk, v,  mva);
                qua = fmaf(gk, u2, qua);
                qva = fmaf(gk, v2, qva);
            }
            if (k >= 1) {
                float gk = g[k - 1];
                mub = fmaf(gk, u,  mub);
                mvb = fmaf(gk, v,  mvb);
                qub = fmaf(gk, u2, qub);
                qvb = fmaf(gk, v2, qvb);
            }
        }
        int rx = (r & 1) << 2;
        *(float4*)&hb[HS * r + ((4 * c0)     ^ rx)] = make_float4(mua, mva, qua, qva);
        *(float4*)&hb[HS * r + ((4 * c0 + 4) ^ rx)] = make_float4(mub, mvb, qub, qvb);
    }
    __syncthreads();

    // ---- Phase 3: vertical 11-tap, 256 threads x 4 stacked rows ----
    // 14 b128 reads/thread; one read yields all 4 quantities.
    float ssum = 0.f, csum = 0.f;
    {
        int c  = tid & 15;              // output col 0..15
        int r0 = (tid >> 4) << 2;       // output rows r0..r0+3
        float MU[4] = {0, 0, 0, 0}, MV[4] = {0, 0, 0, 0};
        float QU[4] = {0, 0, 0, 0}, QV[4] = {0, 0, 0, 0};
        #pragma unroll
        for (int k = 0; k < 14; ++k) {
            int R = r0 + k;
            float4 h = *(const float4*)&hb[HS * R + ((4 * c) ^ ((R & 1) << 2))];
            #pragma unroll
            for (int j = 0; j < 4; ++j) {
                int t = k - j;
                if (t >= 0 && t < 11) {
                    float gk = g[t];
                    MU[j] = fmaf(gk, h.x, MU[j]);
                    MV[j] = fmaf(gk, h.y, MV[j]);
                    QU[j] = fmaf(gk, h.z, QU[j]);
                    QV[j] = fmaf(gk, h.w, QV[j]);
                }
            }
        }
        #pragma unroll
        for (int j = 0; j < 4; ++j) {
            if (ty + r0 + j < H) {      // guard: tile may overhang (level 4, H=32)
                float P = MU[j] * MU[j], Qm = MV[j] * MV[j];
                float A = 0.5f * (P - Qm);            // 2*mu1*mu2
                float B = 0.5f * (P + Qm);            // mu1^2 + mu2^2
                float su = 0.5f * (QU[j] + QV[j]);    // E[x^2] + E[y^2]
                float sd = 0.5f * (QU[j] - QV[j]);    // 2*E[xy]
                float n1 = A + SC1;
                float d1 = B + SC1;
                float n2 = sd - A + SC2;              // 2*sigma12 + C2
                float d2 = su - B + SC2;              // sigma1^2+sigma2^2 + C2
                float inv = 1.f / (d1 * d2);
                csum += n2 * d1 * inv;
                ssum += n1 * n2 * inv;
            }
        }
    }

    // ---- Block reduction -> one atomic pair per block ----
    #pragma unroll
    for (int off = 32; off; off >>= 1) {
        ssum += __shfl_down(ssum, off);
        csum += __shfl_down(csum, off);
    }
    const int wid = tid >> 6, lane = tid & 63;
    if (lane == 0) { sm->rbuf[wid * 2] = ssum; sm->rbuf[wid * 2 + 1] = csum; }
    __syncthreads();
    if (tid == 0) {
        float S = sm->rbuf[0] + sm->rbuf[2] + sm->rbuf[4] + sm->rbuf[6];
        float C = sm->rbuf[1] + sm->rbuf[3] + sm->rbuf[5] + sm->rbuf[7];
        int slot = (blockIdx.x + blockIdx.y * 7 + blockIdx.z * 13) & (NSLOT - 1);
        atomicAdd(&accum[(2 * level) * NSLOT + slot], S);
        atomicAdd(&accum[(2 * level + 1) * NSLOT + slot], C);
    }
}

// ---------------- level 0: 16x64 tiles, SSIM + full pyramid ---------------
// Bijective XCD swizzle (nwg = 12288 = 8*1536): consecutive launch-order
// blocks (-> different XCDs under %8 round-robin) get far-apart tiles;
// same-XCD neighbors raster within a plane sharing halo cols -> L2 reuse.
__global__ __launch_bounds__(256, 4) void ssim_l0(
        const float* __restrict__ img1, const float* __restrict__ img2,
        const float* __restrict__ window, float* __restrict__ accum,
        float* __restrict__ l1a, float* __restrict__ l1b,
        float* __restrict__ l2a, float* __restrict__ l2b,
        float* __restrict__ l3a, float* __restrict__ l3b,
        float* __restrict__ l4a, float* __restrict__ l4b)
{
    __shared__ Smem sm;
    const int lin = blockIdx.x + (blockIdx.y << 5) + (blockIdx.z << 8);
    const int swz = (lin & 7) * 1536 + (lin >> 3);
    const int plane = swz >> 8;
    const int rem   = swz & 255;
    const int tyi   = rem >> 5;
    const int txi   = rem & 31;
    ssim_tile(&sm,
              img1 + (size_t)plane * 512 * 512,
              img2 + (size_t)plane * 512 * 512,
              512, 512, txi * TW, tyi * THT, 0,
              window, accum,
              l1a + (size_t)plane * 256 * 256, l1b + (size_t)plane * 256 * 256,
              l2a + (size_t)plane * 128 * 128, l2b + (size_t)plane * 128 * 128,
              l3a + (size_t)plane * 64 * 64,   l3b + (size_t)plane * 64 * 64,
              l4a + (size_t)plane * 32 * 32,   l4b + (size_t)plane * 32 * 32);
}

// ---------------- combined levels 1-4: 16x64 tiles (r3-verified) ----------
// l1: 16x4=64 tiles, l2: 8x2=16, l3: 4x1=4, l4: 2x1=2 -> 86 blocks/plane.
__global__ __launch_bounds__(256, 4) void ssim_rest(
        const float* __restrict__ l1a, const float* __restrict__ l1b,
        const float* __restrict__ l2a, const float* __restrict__ l2b,
        const float* __restrict__ l3a, const float* __restrict__ l3b,
        const float* __restrict__ l4a, const float* __restrict__ l4b,
        const float* __restrict__ window, float* __restrict__ accum)
{
    __shared__ Smem sm;
    const int x = blockIdx.x;        // 0..85 tile id within plane
    const int plane = blockIdx.z;
    int level, H, tix, tiy;
    const float *b1, *b2;
    if (x < 64)      { level = 1; H = 256; tix = x & 15;           tiy = x >> 4;      b1 = l1a; b2 = l1b; }
    else if (x < 80) { level = 2; H = 128; int i = x - 64; tix = i & 7; tiy = i >> 3; b1 = l2a; b2 = l2b; }
    else if (x < 84) { level = 3; H = 64;  int i = x - 80; tix = i;     tiy = 0;      b1 = l3a; b2 = l3b; }
    else             { level = 4; H = 32;  int i = x - 84; tix = i;     tiy = 0;      b1 = l4a; b2 = l4b; }
    const float* p1 = b1 + (size_t)plane * H * H;
    const float* p2 = b2 + (size_t)plane * H * H;
    ssim_tile(&sm, p1, p2, H, H, tix * TW, tiy * THT, level,
              window, accum,
              nullptr, nullptr, nullptr, nullptr,
              nullptr, nullptr, nullptr, nullptr);
}

// ---------------- final weighted product ----------------------------------
__global__ void finalize_kernel(const float* __restrict__ accum, float* __restrict__ out) {
    int t = threadIdx.x;   // 64 threads
    float sums[10];
    #pragma unroll
    for (int i = 0; i < 10; ++i) {
        float v = accum[i * NSLOT + t];
        #pragma unroll
        for (int off = 32; off; off >>= 1) v += __shfl_down(v, off);
        sums[i] = v;
    }
    if (t == 0) {
        const float w[5] = {0.0448f, 0.2856f, 0.3001f, 0.2363f, 0.1333f};
        float res = 1.f;
        #pragma unroll
        for (int L = 0; L < 4; ++L) {
            float dim = (float)(512 >> L);
            float cnt = (float)PLANES * dim * dim;
            res *= powf(sums[2 * L + 1] / cnt, w[L]);   // cs mean, levels 0..3
        }
        float cnt4 = (float)PLANES * 32.f * 32.f;
        res *= powf(sums[8] / cnt4, w[4]);              // ssim mean, level 4
        out[0] = res;
    }
}

// ---------------- launch ---------------------------------------------------
extern "C" void kernel_launch(void* const* d_in, const int* in_sizes, int n_in,
                              void* d_out, int out_size, void* d_ws, size_t ws_size,
                              hipStream_t stream) {
    const float* img1   = (const float*)d_in[0];
    const float* img2   = (const float*)d_in[1];
    const float* window = (const float*)d_in[2];
    float* out = (float*)d_out;
    float* ws  = (float*)d_ws;

    float* accum = ws;   // 640 floats
    const size_t S1 = (size_t)PLANES * 256 * 256;
    const size_t S2 = (size_t)PLANES * 128 * 128;
    const size_t S3 = (size_t)PLANES * 64 * 64;
    const size_t S4 = (size_t)PLANES * 32 * 32;
    float* l1a = ws + 1024;    float* l1b = l1a + S1;
    float* l2a = l1b + S1;     float* l2b = l2a + S2;
    float* l3a = l2b + S2;     float* l3b = l3a + S3;
    float* l4a = l3b + S3;     float* l4b = l4a + S4;

    hipMemsetAsync(accum, 0, 10 * NSLOT * sizeof(float), stream);

    ssim_l0<<<dim3(512 / TW, 512 / THT, PLANES), 256, 0, stream>>>(
        img1, img2, window, accum,
        l1a, l1b, l2a, l2b, l3a, l3b, l4a, l4b);

    ssim_rest<<<dim3(86, 1, PLANES), 256, 0, stream>>>(
        l1a, l1b, l2a, l2b, l3a, l3b, l4a, l4b, window, accum);

    finalize_kernel<<<1, 64, 0, stream>>>(accum, out);
}

// Round 6
// 219.395 us; speedup vs baseline: 1.4226x; 1.0142x over previous
//
#include <hip/hip_runtime.h>
#include <math.h>

#define TW 16                // tile width (output cols)
#define THT 64               // tile height (r4 post-mortem: THT=32 regressed 37%)
#define HRT 74               // THT + 10
#define SS 66                // sb row stride: 32 px * 2 (u,v interleaved) + 2 pad.
                             // b64 slot stride 33 == 1 mod 16 -> phase-2 taps
                             // uniform 4 lanes/bank (hand-verified r5).
#define HS 64                // hb row stride: 16 cols * 4 packed (mu,mv,qu,qv).
                             // Column-quad XOR by row parity: b128 read/write uniform-8.
#define SC1 0.0001f
#define SC2 0.0009f
#define PLANES 48
#define NSLOT 64

// Packed-FP32 pairs: every FMA in this kernel pairs (u,v)/(mu,mv)/(qu,qv)
// with a shared Gaussian weight -> v_pk_fma_f32 halves FMA issue slots.
// Same accumulation order per component -> bitwise-identical results.
typedef float v2f __attribute__((ext_vector_type(2)));

// u/v transform staged at load: u=a+b, v=a-b, INTERLEAVED in one buffer.
// Staged window = cols tx-8 .. tx+23 (32 px): 16B-aligned -> float4 global loads.
// Output col c uses staged cols c+3 .. c+13.
struct alignas(16) Smem {
    float sb[HRT * SS];      // (u,v) interleaved: staged px j at [SS*r + 2j]
    float hb[HRT * HS];      // float4 (mu,mv,qu,qv) at [HS*r + (4c ^ ((r&1)<<2))]
    float rbuf[8];
};
// (74*66 + 74*64 + 8)*4 = 38544 B -> 4 blocks/CU.

__device__ __forceinline__ void ssim_tile(
        Smem* sm,
        const float* __restrict__ p1, const float* __restrict__ p2,
        int H, int W, int tx, int ty, int level,
        const float* __restrict__ window,
        float* __restrict__ accum,
        float* __restrict__ l1a, float* __restrict__ l1b,   // plane-offset outs (or null)
        float* __restrict__ l2a, float* __restrict__ l2b,
        float* __restrict__ l3a, float* __restrict__ l3b,
        float* __restrict__ l4a, float* __restrict__ l4b)
{
    const int tid = threadIdx.x;
    float* sb = sm->sb;
    float* hb = sm->hb;

    // 1D gaussian from 2D window: g[k] = w2[5][k]/sqrt(w2[5][5])
    float g[11];
    {
        float invg5 = 1.0f / sqrtf(window[60]);
        #pragma unroll
        for (int k = 0; k < 11; ++k) g[k] = window[55 + k] * invg5;
    }

    // ---- Phase 1: stage halo tile (HRT x 32 px) as interleaved (u,v) ----
    const bool interior = (ty >= 5) && (ty + HRT - 6 < H) &&
                          (tx >= 8) && (tx + 24 <= W);
    if (interior) {
        // 592 items, float4 loads (16B-aligned: tx-8+4j == 0 mod 4)
        for (int s = tid; s < HRT * 8; s += 256) {
            int r = s >> 3, j = s & 7;
            size_t o = (size_t)(ty + r - 5) * W + (tx - 8 + 4 * j);
            float4 a = *(const float4*)(p1 + o);
            float4 b = *(const float4*)(p2 + o);
            float* d = &sb[SS * r + 8 * j];
            *(float2*)(d)     = make_float2(a.x + b.x, a.x - b.x);
            *(float2*)(d + 2) = make_float2(a.y + b.y, a.y - b.y);
            *(float2*)(d + 4) = make_float2(a.z + b.z, a.z - b.z);
            *(float2*)(d + 6) = make_float2(a.w + b.w, a.w - b.w);
        }
    } else {
        // boundary: float2 slots with whole-slot guard (gx even, W even)
        for (int s = tid; s < HRT * 16; s += 256) {
            int r = s >> 4, j = s & 15;
            int gy = ty + r - 5;
            int gx = tx - 8 + 2 * j;
            float2 v1 = make_float2(0.f, 0.f), v2 = make_float2(0.f, 0.f);
            if ((unsigned)gy < (unsigned)H && (unsigned)gx < (unsigned)W) {
                size_t o = (size_t)gy * W + gx;
                v1 = *(const float2*)(p1 + o);
                v2 = *(const float2*)(p2 + o);
            }
            float* d = &sb[SS * r + 4 * j];
            *(float2*)(d)     = make_float2(v1.x + v2.x, v1.x - v2.x);
            *(float2*)(d + 2) = make_float2(v1.y + v2.y, v1.y - v2.y);
        }
    }
    __syncthreads();

    // ---- Fused 2x2 avg-pool -> l1 (all 256 threads; a=(u+v)/2) ----
    if (l1a) {
        int pc = tid & 7;          // pooled col 0..7
        int pr = tid >> 3;         // pooled row 0..31
        int r  = 2 * pr + 5;
        int x0 = 2 * (2 * pc + 8); // staged col of original px 2pc
        const v2f* r0p = (const v2f*)&sb[SS * r + x0];
        const v2f* r1p = (const v2f*)&sb[SS * (r + 1) + x0];
        v2f s = (r0p[0] + r0p[1]) + (r1p[0] + r1p[1]);   // 3 pk_add
        int W2 = W >> 1;
        size_t o = (size_t)((ty >> 1) + pr) * W2 + (tx >> 1) + pc;
        l1a[o] = 0.125f * (s.x + s.y);
        l1b[o] = 0.125f * (s.x - s.y);
    }

    // ---- Pyramid l2/l3/l4 on wave 3 (64 l2 px = full wave) ----
    if (l1a && tid >= 192) {
        const int lane = tid - 192;
        int qr = lane >> 2, qc = lane & 3;      // l2 px = 4x4 mean of originals
        int rb = 4 * qr + 5, cb = 4 * qc + 8;   // cb in staged-col space
        v2f acc = {0.f, 0.f};
        #pragma unroll
        for (int i = 0; i < 4; ++i) {
            int ii = (i + qc) & 3;              // sum-invariant rotations:
            #pragma unroll
            for (int j = 0; j < 4; ++j) {
                int jr = (j + qr) & 3;          // spread banks across lanes
                acc += *(const v2f*)&sb[SS * (rb + ii) + 2 * (cb + jr)];
            }
        }
        float v2a = 0.03125f * (acc.x + acc.y), v2b = 0.03125f * (acc.x - acc.y);
        {
            int W4 = W >> 2;
            size_t o = (size_t)((ty >> 2) + qr) * W4 + (tx >> 2) + qc;
            l2a[o] = v2a;
            l2b[o] = v2b;
        }
        float v3a, v3b;
        {
            int tr = (lane >> 1) & 7, tc = lane & 1;
            int l00 = 8 * tr + 2 * tc;
            v3a = 0.25f * (__shfl(v2a, l00) + __shfl(v2a, l00 + 1) +
                           __shfl(v2a, l00 + 4) + __shfl(v2a, l00 + 5));
            v3b = 0.25f * (__shfl(v2b, l00) + __shfl(v2b, l00 + 1) +
                           __shfl(v2b, l00 + 4) + __shfl(v2b, l00 + 5));
            if (lane < 16) {
                int W8 = W >> 3;
                size_t o = (size_t)((ty >> 3) + tr) * W8 + (tx >> 3) + tc;
                l3a[o] = v3a;
                l3b[o] = v3b;
            }
        }
        {
            int ur = lane & 3;
            float v4a = 0.25f * (__shfl(v3a, 4 * ur) + __shfl(v3a, 4 * ur + 1) +
                                 __shfl(v3a, 4 * ur + 2) + __shfl(v3a, 4 * ur + 3));
            float v4b = 0.25f * (__shfl(v3b, 4 * ur) + __shfl(v3b, 4 * ur + 1) +
                                 __shfl(v3b, 4 * ur + 2) + __shfl(v3b, 4 * ur + 3));
            if (lane < 4) {
                int W16 = W >> 4;
                size_t o = (size_t)((ty >> 4) + ur) * W16 + (tx >> 4);
                l4a[o] = v4a;
                l4b[o] = v4b;
            }
        }
    }

    // ---- Phase 2: horizontal 11-tap, 592 items over 256 threads ----
    // Packed: per tap 1 pk_mul + 4 pk_fma (vs 2 mul + 8 fma scalar).
    for (int gi = tid; gi < HRT * 8; gi += 256) {
        int r  = gi >> 3;
        int c0 = (gi & 7) << 1;
        const v2f* src = (const v2f*)&sb[SS * r + 2 * (c0 + 3)];
        v2f am_a = {0,0}, aq_a = {0,0};   // (mu,mv), (qu,qv) for col c0
        v2f am_b = {0,0}, aq_b = {0,0};   // same for col c0+1
        #pragma unroll
        for (int k = 0; k < 12; ++k) {              // staged cols c0+3 .. c0+14
            v2f uv = src[k];
            v2f sq = uv * uv;
            if (k < 11) {
                v2f gg = {g[k], g[k]};
                am_a += gg * uv;
                aq_a += gg * sq;
            }
            if (k >= 1) {
                v2f gg = {g[k - 1], g[k - 1]};
                am_b += gg * uv;
                aq_b += gg * sq;
            }
        }
        int rx = (r & 1) << 2;
        *(float4*)&hb[HS * r + ((4 * c0)     ^ rx)] = make_float4(am_a.x, am_a.y, aq_a.x, aq_a.y);
        *(float4*)&hb[HS * r + ((4 * c0 + 4) ^ rx)] = make_float4(am_b.x, am_b.y, aq_b.x, aq_b.y);
    }
    __syncthreads();

    // ---- Phase 3: vertical 11-tap, 256 threads x 4 stacked rows ----
    // 14 b128 reads/thread; packed accumulate: 88 pk_fma vs 176 fma.
    float ssum = 0.f, csum = 0.f;
    {
        int c  = tid & 15;              // output col 0..15
        int r0 = (tid >> 4) << 2;       // output rows r0..r0+3
        v2f M[4] = {{0,0},{0,0},{0,0},{0,0}};   // (MU,MV)
        v2f Q[4] = {{0,0},{0,0},{0,0},{0,0}};   // (QU,QV)
        #pragma unroll
        for (int k = 0; k < 14; ++k) {
            int R = r0 + k;
            float4 h = *(const float4*)&hb[HS * R + ((4 * c) ^ ((R & 1) << 2))];
            v2f hm = {h.x, h.y};
            v2f hq = {h.z, h.w};
            #pragma unroll
            for (int j = 0; j < 4; ++j) {
                int t = k - j;
                if (t >= 0 && t < 11) {
                    v2f gg = {g[t], g[t]};
                    M[j] += gg * hm;
                    Q[j] += gg * hq;
                }
            }
        }
        #pragma unroll
        for (int j = 0; j < 4; ++j) {
            if (ty + r0 + j < H) {      // guard: tile may overhang (level 4, H=32)
                float P = M[j].x * M[j].x, Qm = M[j].y * M[j].y;
                float A = 0.5f * (P - Qm);            // 2*mu1*mu2
                float B = 0.5f * (P + Qm);            // mu1^2 + mu2^2
                float su = 0.5f * (Q[j].x + Q[j].y);  // E[x^2] + E[y^2]
                float sd = 0.5f * (Q[j].x - Q[j].y);  // 2*E[xy]
                float n1 = A + SC1;
                float d1 = B + SC1;
                float n2 = sd - A + SC2;              // 2*sigma12 + C2
                float d2 = su - B + SC2;              // sigma1^2+sigma2^2 + C2
                float inv = 1.f / (d1 * d2);
                csum += n2 * d1 * inv;
                ssum += n1 * n2 * inv;
            }
        }
    }

    // ---- Block reduction -> one atomic pair per block ----
    #pragma unroll
    for (int off = 32; off; off >>= 1) {
        ssum += __shfl_down(ssum, off);
        csum += __shfl_down(csum, off);
    }
    const int wid = tid >> 6, lane = tid & 63;
    if (lane == 0) { sm->rbuf[wid * 2] = ssum; sm->rbuf[wid * 2 + 1] = csum; }
    __syncthreads();
    if (tid == 0) {
        float S = sm->rbuf[0] + sm->rbuf[2] + sm->rbuf[4] + sm->rbuf[6];
        float C = sm->rbuf[1] + sm->rbuf[3] + sm->rbuf[5] + sm->rbuf[7];
        int slot = (blockIdx.x + blockIdx.y * 7 + blockIdx.z * 13) & (NSLOT - 1);
        atomicAdd(&accum[(2 * level) * NSLOT + slot], S);
        atomicAdd(&accum[(2 * level + 1) * NSLOT + slot], C);
    }
}

// ---------------- level 0: 16x64 tiles, SSIM + full pyramid ---------------
// Bijective XCD swizzle (nwg = 12288 = 8*1536): verified r5 (FETCH -74%).
__global__ __launch_bounds__(256, 4) void ssim_l0(
        const float* __restrict__ img1, const float* __restrict__ img2,
        const float* __restrict__ window, float* __restrict__ accum,
        float* __restrict__ l1a, float* __restrict__ l1b,
        float* __restrict__ l2a, float* __restrict__ l2b,
        float* __restrict__ l3a, float* __restrict__ l3b,
        float* __restrict__ l4a, float* __restrict__ l4b)
{
    __shared__ Smem sm;
    const int lin = blockIdx.x + (blockIdx.y << 5) + (blockIdx.z << 8);
    const int swz = (lin & 7) * 1536 + (lin >> 3);
    const int plane = swz >> 8;
    const int rem   = swz & 255;
    const int tyi   = rem >> 5;
    const int txi   = rem & 31;
    ssim_tile(&sm,
              img1 + (size_t)plane * 512 * 512,
              img2 + (size_t)plane * 512 * 512,
              512, 512, txi * TW, tyi * THT, 0,
              window, accum,
              l1a + (size_t)plane * 256 * 256, l1b + (size_t)plane * 256 * 256,
              l2a + (size_t)plane * 128 * 128, l2b + (size_t)plane * 128 * 128,
              l3a + (size_t)plane * 64 * 64,   l3b + (size_t)plane * 64 * 64,
              l4a + (size_t)plane * 32 * 32,   l4b + (size_t)plane * 32 * 32);
}

// ---------------- combined levels 1-4: 16x64 tiles (r3-verified) ----------
// l1: 16x4=64 tiles, l2: 8x2=16, l3: 4x1=4, l4: 2x1=2 -> 86 blocks/plane.
__global__ __launch_bounds__(256, 4) void ssim_rest(
        const float* __restrict__ l1a, const float* __restrict__ l1b,
        const float* __restrict__ l2a, const float* __restrict__ l2b,
        const float* __restrict__ l3a, const float* __restrict__ l3b,
        const float* __restrict__ l4a, const float* __restrict__ l4b,
        const float* __restrict__ window, float* __restrict__ accum)
{
    __shared__ Smem sm;
    const int x = blockIdx.x;        // 0..85 tile id within plane
    const int plane = blockIdx.z;
    int level, H, tix, tiy;
    const float *b1, *b2;
    if (x < 64)      { level = 1; H = 256; tix = x & 15;           tiy = x >> 4;      b1 = l1a; b2 = l1b; }
    else if (x < 80) { level = 2; H = 128; int i = x - 64; tix = i & 7; tiy = i >> 3; b1 = l2a; b2 = l2b; }
    else if (x < 84) { level = 3; H = 64;  int i = x - 80; tix = i;     tiy = 0;      b1 = l3a; b2 = l3b; }
    else             { level = 4; H = 32;  int i = x - 84; tix = i;     tiy = 0;      b1 = l4a; b2 = l4b; }
    const float* p1 = b1 + (size_t)plane * H * H;
    const float* p2 = b2 + (size_t)plane * H * H;
    ssim_tile(&sm, p1, p2, H, H, tix * TW, tiy * THT, level,
              window, accum,
              nullptr, nullptr, nullptr, nullptr,
              nullptr, nullptr, nullptr, nullptr);
}

// ---------------- final weighted product ----------------------------------
__global__ void finalize_kernel(const float* __restrict__ accum, float* __restrict__ out) {
    int t = threadIdx.x;   // 64 threads
    float sums[10];
    #pragma unroll
    for (int i = 0; i < 10; ++i) {
        float v = accum[i * NSLOT + t];
        #pragma unroll
        for (int off = 32; off; off >>= 1) v += __shfl_down(v, off);
        sums[i] = v;
    }
    if (t == 0) {
        const float w[5] = {0.0448f, 0.2856f, 0.3001f, 0.2363f, 0.1333f};
        float res = 1.f;
        #pragma unroll
        for (int L = 0; L < 4; ++L) {
            float dim = (float)(512 >> L);
            float cnt = (float)PLANES * dim * dim;
            res *= powf(sums[2 * L + 1] / cnt, w[L]);   // cs mean, levels 0..3
        }
        float cnt4 = (float)PLANES * 32.f * 32.f;
        res *= powf(sums[8] / cnt4, w[4]);              // ssim mean, level 4
        out[0] = res;
    }
}

// ---------------- launch ---------------------------------------------------
extern "C" void kernel_launch(void* const* d_in, const int* in_sizes, int n_in,
                              void* d_out, int out_size, void* d_ws, size_t ws_size,
                              hipStream_t stream) {
    const float* img1   = (const float*)d_in[0];
    const float* img2   = (const float*)d_in[1];
    const float* window = (const float*)d_in[2];
    float* out = (float*)d_out;
    float* ws  = (float*)d_ws;

    float* accum = ws;   // 640 floats
    const size_t S1 = (size_t)PLANES * 256 * 256;
    const size_t S2 = (size_t)PLANES * 128 * 128;
    const size_t S3 = (size_t)PLANES * 64 * 64;
    const size_t S4 = (size_t)PLANES * 32 * 32;
    float* l1a = ws + 1024;    float* l1b = l1a + S1;
    float* l2a = l1b + S1;     float* l2b = l2a + S2;
    float* l3a = l2b + S2;     float* l3b = l3a + S3;
    float* l4a = l3b + S3;     float* l4b = l4a + S4;

    hipMemsetAsync(accum, 0, 10 * NSLOT * sizeof(float), stream);

    ssim_l0<<<dim3(512 / TW, 512 / THT, PLANES), 256, 0, stream>>>(
        img1, img2, window, accum,
        l1a, l1b, l2a, l2b, l3a, l3b, l4a, l4b);

    ssim_rest<<<dim3(86, 1, PLANES), 256, 0, stream>>>(
        l1a, l1b, l2a, l2b, l3a, l3b, l4a, l4b, window, accum);

    finalize_kernel<<<1, 64, 0, stream>>>(accum, out);
}